// Round 16
// baseline (286.723 us; speedup 1.0000x reference)
//
#include <hip/hip_runtime.h>

// ModelQuantLinear: int8-act × int4-weight per-tensor quantized linear, 8192×4096 @ 4096×4096^T.
// i8 GEMM via mfma_i32_32x32x32_i8. 256x128 tile, BK=128B, 8 waves (2Mx4N, 128x32/wave,
// acc=64 regs), SINGLE-buffered 51KB LDS -> launch_bounds(512,4) gives 2 independent
// blocks/CU (4 waves/SIMD): one block's stage/vmcnt/lgkm stalls hide under the other block's
// MFMA (cross-BLOCK overlap — r13's same-block waves were barrier-lockstepped and didn't help).
// Tile loop: stage-all -> vmcnt(0)+barrier -> 4 free-run phases (no intra-tile barriers, no
// asm lgkm; no LDS writes during compute so compiler-counted waits suffice) -> end barrier.
// Epilogue writes Y bf16 to ws.

typedef int v4i __attribute__((ext_vector_type(4)));
typedef int v16i __attribute__((ext_vector_type(16)));

#define AS1(p) ((const __attribute__((address_space(1))) void*)(p))
#define AS3(p) ((__attribute__((address_space(3))) void*)(p))

#define GM 8192
#define GN 4096
#define GK 4096
#define NWG 1024  // (8192/256)*(4096/128)
#define CH 1088   // chunk stride: 8 rows x 128B + 64B pad (r10 layout)
#define HT 17408  // half-tile: 16 chunks x 1088

// ---------------- fused max|X|,max|W| (block ranges; float4, wave+block reduce, 1 atomic) ----
__global__ __launch_bounds__(256) void maxabs2_kernel(const float* __restrict__ x, int n4x,
                                                      unsigned* __restrict__ slotx,
                                                      const float* __restrict__ w, int n4w,
                                                      unsigned* __restrict__ slotw) {
  __shared__ float red[4];
  const float4* src;
  unsigned* slot;
  int n4, bid, nb;
  if (blockIdx.x < 1024) { src = (const float4*)x; slot = slotx; n4 = n4x; bid = blockIdx.x; nb = 1024; }
  else                   { src = (const float4*)w; slot = slotw; n4 = n4w; bid = blockIdx.x - 1024; nb = 512; }
  int tid = bid * 256 + threadIdx.x;
  int stride = nb * 256;
  float m = 0.0f;
  for (int i = tid; i < n4; i += stride) {
    float4 v = src[i];
    m = fmaxf(m, fmaxf(fmaxf(fabsf(v.x), fabsf(v.y)), fmaxf(fabsf(v.z), fabsf(v.w))));
  }
  for (int off = 32; off; off >>= 1) m = fmaxf(m, __shfl_xor(m, off));
  if ((threadIdx.x & 63) == 0) red[threadIdx.x >> 6] = m;
  __syncthreads();
  if (threadIdx.x == 0)
    atomicMax(slot, __float_as_uint(fmaxf(fmaxf(red[0], red[1]), fmaxf(red[2], red[3]))));
}

// ---------------- fused quantize X->int8, W->int4-in-int8 (reciprocal-mul) ------------------
__global__ __launch_bounds__(256) void quant2_kernel(const float* __restrict__ x,
                                                     signed char* __restrict__ qx, int n4x,
                                                     const unsigned* __restrict__ slotx,
                                                     const float* __restrict__ w,
                                                     signed char* __restrict__ qw, int n4w,
                                                     const unsigned* __restrict__ slotw) {
  const float4* src;
  int* dst;
  int n4, bid, nb;
  float qmaxv, qlo, qhi;
  const unsigned* slot;
  if (blockIdx.x < 1024) {
    src = (const float4*)x; dst = (int*)qx; n4 = n4x; bid = blockIdx.x; nb = 1024;
    slot = slotx; qmaxv = 127.0f; qlo = -128.0f; qhi = 127.0f;
  } else {
    src = (const float4*)w; dst = (int*)qw; n4 = n4w; bid = blockIdx.x - 1024; nb = 512;
    slot = slotw; qmaxv = 7.0f; qlo = -8.0f; qhi = 7.0f;
  }
  float s = fmaxf(__uint_as_float(*slot) / qmaxv, 1e-8f);
  float inv = 1.0f / s;
  int tid = bid * 256 + threadIdx.x;
  int stride = nb * 256;
  for (int i = tid; i < n4; i += stride) {
    float4 v = src[i];
    int a0 = (int)fminf(fmaxf(rintf(v.x * inv), qlo), qhi);
    int a1 = (int)fminf(fmaxf(rintf(v.y * inv), qlo), qhi);
    int a2 = (int)fminf(fmaxf(rintf(v.z * inv), qlo), qhi);
    int a3 = (int)fminf(fmaxf(rintf(v.w * inv), qlo), qhi);
    dst[i] = (a0 & 255) | ((a1 & 255) << 8) | ((a2 & 255) << 16) | ((a3 & 255) << 24);
  }
}

// ---------------- i8 GEMM, 256x128 tile, BK=128 B, 8 waves (2Mx4N), 32x32x32 MFMA -----------
// Wave (wr,wc), wr in 0..1, wc in 0..3: rows [wr*128, +128), cols [wc*32, +32).
// Per tile t (single LDS buffer; 2 barriers/tile):
//   STAGE A0,A1,B (6 gload_lds/wave); vmcnt(0); barrier
//   for ks=0..3: af[4]+bf (5 ds_read_b128); 4 MFMA   [free-run; compiler-counted lgkm]
//   barrier  (WAR: all reads consumed by MFMAs -- HW interlock -- before any wave restages)
// Cross-block overlap: LDS 51KB + acc 64 regs -> 2 blocks/CU, 4 waves/SIMD from INDEPENDENT
// blocks; one block's stage/wait stalls hide under the other's MFMA clusters (m114).
// LDS addr (row hr in half, phys g): (hr>>3)*1088 + (hr&7)*128 + g*16, g = g_log ^ (hr&7);
// inverse swizzle on the global source granule (rule 21). Staging instr i of wave w writes
// rows {i*64 + w*8 .. +7} of a half linearly at chunk base (i*8+w)*1088.
// C/D layout (m74/m101, dtype-independent): col=lane&31, row=(r&3)+8*(r>>2)+4*(lane>>5).
template <bool BF16OUT>
__global__ __launch_bounds__(512, 4) void gemm_i8_kernel(const signed char* __restrict__ Xq,
                                                         const signed char* __restrict__ Wq,
                                                         const float* __restrict__ bias,
                                                         const unsigned* __restrict__ slots,
                                                         void* __restrict__ Yout,
                                                         unsigned* __restrict__ maxY) {
  __shared__ signed char smem[3 * HT];  // A half0, A half1, B  (52224 B -> 2 blocks/CU)
  const int tid = threadIdx.x;
  const int wid = tid >> 6, lane = tid & 63;
  const int wr = wid >> 2, wc = wid & 3;
  const int l31 = lane & 31, lg2 = lane >> 5;

  const int bid = (int)blockIdx.x;
  const int swz = (bid & 7) * (NWG / 8) + (bid >> 3);  // XCD-aware bijective (1024%8==0)
  const int brow = (swz >> 5) * 256;  // 32 row-tiles
  const int bcol = (swz & 31) * 128;  // 32 col-tiles

  const int srr = tid >> 3;               // staging row 0..63 (instr 2 adds 64)
  const int sgl = (tid & 7) ^ (srr & 7);  // inverse-swizzled source granule

  // per-frag LDS row-base offsets / swizzle keys (row-in-half = mm*32 + l31 for A)
  int aoff[4], asw[4], boffv, bswv;
#pragma unroll
  for (int mm = 0; mm < 4; ++mm) {
    int hr = mm * 32 + l31;
    aoff[mm] = (hr >> 3) * CH + (hr & 7) * 128;
    asw[mm] = hr & 7;
  }
  {
    int hr = wc * 32 + l31;
    boffv = (hr >> 3) * CH + (hr & 7) * 128;
    bswv = hr & 7;
  }

#define ASLOT(h) (smem + (h) * HT)
#define BSLOT() (smem + 2 * HT)
// one half-tile (128 rows): 2 x global_load_lds(16B) per wave; chunk base (i*8+wid)*1088
#define STAGE(gptr, grow0, kofs, slot)                                                        \
  {                                                                                           \
    const signed char* _s0 = (gptr) + (size_t)((grow0) + srr) * GK + (kofs) + sgl * 16;       \
    __builtin_amdgcn_global_load_lds(AS1(_s0), AS3((slot) + wid * CH), 16, 0, 0);             \
    __builtin_amdgcn_global_load_lds(AS1(_s0 + (size_t)64 * GK),                              \
                                     AS3((slot) + (8 + wid) * CH), 16, 0, 0);                 \
  }

  v16i acc[4] = {};

  for (int t = 0; t < 32; ++t) {
    const int kof = t * 128;

    // ---- stage tile t into the single buffer, wait, sync
    STAGE(Xq, brow, kof, ASLOT(0));
    STAGE(Xq, brow + 128, kof, ASLOT(1));
    STAGE(Wq, bcol, kof, BSLOT());
    asm volatile("s_waitcnt vmcnt(0)" ::: "memory");
    __builtin_amdgcn_s_barrier();
    asm volatile("" ::: "memory");

    // ---- free-run compute: 4 k-slices, no barriers, compiler-counted lgkm waits
    const signed char* abase = ASLOT(wr);
#pragma unroll
    for (int ks = 0; ks < 4; ++ks) {
      v4i af[4], bf;
#pragma unroll
      for (int mm = 0; mm < 4; ++mm)
        af[mm] = *(const v4i*)(abase + aoff[mm] + (((ks * 2 + lg2) ^ asw[mm]) << 4));
      bf = *(const v4i*)(BSLOT() + boffv + (((ks * 2 + lg2) ^ bswv) << 4));
      __builtin_amdgcn_s_setprio(1);
#pragma unroll
      for (int mm = 0; mm < 4; ++mm)
        acc[mm] = __builtin_amdgcn_mfma_i32_32x32x32_i8(af[mm], bf, acc[mm], 0, 0, 0);
      __builtin_amdgcn_s_setprio(0);
    }
    __builtin_amdgcn_s_barrier();  // WAR: reads consumed before any wave restages
    asm volatile("" ::: "memory");
  }

  // Epilogue: y = acc*(s_in*s_w) + round(b/s_b)*s_b ; track max|y| (block-reduced atomic)
  float s_in = fmaxf(__uint_as_float(slots[0]) / 127.0f, 1e-8f);
  float s_w = fmaxf(__uint_as_float(slots[1]) / 7.0f, 1e-8f);
  float s_b = s_in * s_w;
  int o = bcol + wc * 32 + l31;
  float bdq = rintf(bias[o] / s_b) * s_b;
  float lmax = 0.0f;
#pragma unroll
  for (int m = 0; m < 4; ++m) {
    int rbase = brow + wr * 128 + m * 32 + 4 * lg2;
#pragma unroll
    for (int r = 0; r < 16; ++r) {
      int row = rbase + (r & 3) + 8 * (r >> 2);
      float yv = (float)acc[m][r] * s_b + bdq;
      size_t idx = (size_t)row * GN + o;
      if (BF16OUT) {
        unsigned u = __float_as_uint(yv);
        ((unsigned short*)Yout)[idx] = (unsigned short)((u + 0x7fffu + ((u >> 16) & 1u)) >> 16);
      } else {
        ((float*)Yout)[idx] = yv;
      }
      lmax = fmaxf(lmax, fabsf(yv));
    }
  }
  for (int off = 32; off; off >>= 1) lmax = fmaxf(lmax, __shfl_xor(lmax, off));
  float* fred = (float*)smem;  // final tile's reads drained before last barrier
  if (lane == 0) fred[wid] = lmax;
  __syncthreads();
  if (tid == 0) {
    float m = fred[0];
#pragma unroll
    for (int i = 1; i < 8; ++i) m = fmaxf(m, fred[i]);
    atomicMax(maxY, __float_as_uint(m));
  }
#undef STAGE
#undef ASLOT
#undef BSLOT
}

// ---------------- output quant: bf16 Y in ws -> quantized fp32 d_out -------------------------
__global__ __launch_bounds__(256) void quant_out_bf16_kernel(const unsigned short* __restrict__ yb,
                                                             float* __restrict__ out, int n8,
                                                             const unsigned* __restrict__ slot) {
  float s = fmaxf(__uint_as_float(*slot) / 127.0f, 1e-8f);
  float inv = 1.0f / s;
  int tid = blockIdx.x * blockDim.x + threadIdx.x;
  int stride = gridDim.x * blockDim.x;
  const uint4* y4 = (const uint4*)yb;
  float4* o4 = (float4*)out;
  for (int i = tid; i < n8; i += stride) {
    uint4 v = y4[i];
    float f[8];
    f[0] = __uint_as_float((v.x & 0xffffu) << 16);
    f[1] = __uint_as_float(v.x & 0xffff0000u);
    f[2] = __uint_as_float((v.y & 0xffffu) << 16);
    f[3] = __uint_as_float(v.y & 0xffff0000u);
    f[4] = __uint_as_float((v.z & 0xffffu) << 16);
    f[5] = __uint_as_float(v.z & 0xffff0000u);
    f[6] = __uint_as_float((v.w & 0xffffu) << 16);
    f[7] = __uint_as_float(v.w & 0xffff0000u);
    float4 a, b;
    a.x = fminf(fmaxf(rintf(f[0] * inv), -128.0f), 127.0f) * s;
    a.y = fminf(fmaxf(rintf(f[1] * inv), -128.0f), 127.0f) * s;
    a.z = fminf(fmaxf(rintf(f[2] * inv), -128.0f), 127.0f) * s;
    a.w = fminf(fmaxf(rintf(f[3] * inv), -128.0f), 127.0f) * s;
    b.x = fminf(fmaxf(rintf(f[4] * inv), -128.0f), 127.0f) * s;
    b.y = fminf(fmaxf(rintf(f[5] * inv), -128.0f), 127.0f) * s;
    b.z = fminf(fmaxf(rintf(f[6] * inv), -128.0f), 127.0f) * s;
    b.w = fminf(fmaxf(rintf(f[7] * inv), -128.0f), 127.0f) * s;
    o4[i * 2] = a;
    o4[i * 2 + 1] = b;
  }
}

// fp32 in-place fallback (ws too small for bf16 Y)
__global__ __launch_bounds__(256) void quant_out_kernel(float* __restrict__ y, int n4,
                                                        const unsigned* __restrict__ slot) {
  float s = fmaxf(__uint_as_float(*slot) / 127.0f, 1e-8f);
  float inv = 1.0f / s;
  int tid = blockIdx.x * blockDim.x + threadIdx.x;
  int stride = gridDim.x * blockDim.x;
  float4* y4 = (float4*)y;
  for (int i = tid; i < n4; i += stride) {
    float4 v = y4[i];
    v.x = fminf(fmaxf(rintf(v.x * inv), -128.0f), 127.0f) * s;
    v.y = fminf(fmaxf(rintf(v.y * inv), -128.0f), 127.0f) * s;
    v.z = fminf(fmaxf(rintf(v.z * inv), -128.0f), 127.0f) * s;
    v.w = fminf(fmaxf(rintf(v.w * inv), -128.0f), 127.0f) * s;
    y4[i] = v;
  }
}

extern "C" void kernel_launch(void* const* d_in, const int* in_sizes, int n_in,
                              void* d_out, int out_size, void* d_ws, size_t ws_size,
                              hipStream_t stream) {
  const float* inp = (const float*)d_in[0];  // [8192,4096]
  const float* W = (const float*)d_in[1];    // [4096,4096]
  const float* b = (const float*)d_in[2];    // [4096]
  float* out = (float*)d_out;                // [8192,4096]

  unsigned* slots = (unsigned*)d_ws;  // [0]=max|X|, [1]=max|W|, [2]=max|Y| (float bits)
  signed char* Xq = (signed char*)d_ws + 256;
  signed char* Wq = Xq + (size_t)GM * GK;
  unsigned short* Yb = (unsigned short*)(Wq + (size_t)GN * GK);

  const int nX = GM * GK;
  const int nW = GN * GK;
  const size_t need_bf16 = 256 + (size_t)nX + (size_t)nW + (size_t)GM * GN * 2;
  const bool use_bf16 = ws_size >= need_bf16;

  // zero the atomic-max slots (ws is NOT re-poisoned between timed replays)
  hipMemsetAsync(d_ws, 0, 16, stream);

  maxabs2_kernel<<<1536, 256, 0, stream>>>(inp, nX / 4, slots + 0, W, nW / 4, slots + 1);
  quant2_kernel<<<1536, 256, 0, stream>>>(inp, Xq, nX / 4, slots + 0, W, Wq, nW / 4, slots + 1);

  if (use_bf16) {
    gemm_i8_kernel<true><<<NWG, 512, 0, stream>>>(Xq, Wq, b, slots, (void*)Yb, slots + 2);
    quant_out_bf16_kernel<<<1024, 256, 0, stream>>>(Yb, out, (GM * GN) / 8, slots + 2);
  } else {
    gemm_i8_kernel<false><<<NWG, 512, 0, stream>>>(Xq, Wq, b, slots, (void*)out, slots + 2);
    quant_out_kernel<<<1024, 256, 0, stream>>>(out, (GM * GN) / 4, slots + 2);
  }
}

// Round 17
// 263.855 us; speedup vs baseline: 1.0867x; 1.0867x over previous
//
#include <hip/hip_runtime.h>

// ModelQuantLinear: int8-act × int4-weight per-tensor quantized linear, 8192×4096 @ 4096×4096^T.
// i8 GEMM via mfma_i32_32x32x32_i8, 256x256 tile, BK=128B, 8 waves (2Mx4N) — r10 chassis
// (best known: 138us GEMM) with DEEPER PREFETCH RETIMING: B0+B1(t+1) issued at the gate,
// A0/A1(t+1) at P0/P1, gate waits vmcnt(4) -> youngest drained load is ~2.3 phases (~1500cyc)
// old, fully covering HBM latency (r10's vmcnt(2) drained a ~1-phase-old load every tile).
// Phase shape unchanged: {6 ds_read; <=1 stage; lgkmcnt(0); 8 MFMA; barrier}.
// LDS: 8-row chunks @1088B stride. Epilogue writes Y bf16 to ws.

typedef int v4i __attribute__((ext_vector_type(4)));
typedef int v16i __attribute__((ext_vector_type(16)));

#define AS1(p) ((const __attribute__((address_space(1))) void*)(p))
#define AS3(p) ((__attribute__((address_space(3))) void*)(p))

#define GM 8192
#define GN 4096
#define GK 4096
#define NBN 16    // 4096/256 col tiles
#define NWG 512   // (8192/256)*(4096/256)
#define CH 1088   // chunk stride: 8 rows x 128B + 64B pad
#define HT 17408  // half-tile: 16 chunks x 1088

// ---------------- fused max|X|,max|W| (block ranges; float4, wave+block reduce, 1 atomic) ----
__global__ __launch_bounds__(256) void maxabs2_kernel(const float* __restrict__ x, int n4x,
                                                      unsigned* __restrict__ slotx,
                                                      const float* __restrict__ w, int n4w,
                                                      unsigned* __restrict__ slotw) {
  __shared__ float red[4];
  const float4* src;
  unsigned* slot;
  int n4, bid, nb;
  if (blockIdx.x < 1024) { src = (const float4*)x; slot = slotx; n4 = n4x; bid = blockIdx.x; nb = 1024; }
  else                   { src = (const float4*)w; slot = slotw; n4 = n4w; bid = blockIdx.x - 1024; nb = 512; }
  int tid = bid * 256 + threadIdx.x;
  int stride = nb * 256;
  float m = 0.0f;
  for (int i = tid; i < n4; i += stride) {
    float4 v = src[i];
    m = fmaxf(m, fmaxf(fmaxf(fabsf(v.x), fabsf(v.y)), fmaxf(fabsf(v.z), fabsf(v.w))));
  }
  for (int off = 32; off; off >>= 1) m = fmaxf(m, __shfl_xor(m, off));
  if ((threadIdx.x & 63) == 0) red[threadIdx.x >> 6] = m;
  __syncthreads();
  if (threadIdx.x == 0)
    atomicMax(slot, __float_as_uint(fmaxf(fmaxf(red[0], red[1]), fmaxf(red[2], red[3]))));
}

// ---------------- fused quantize X->int8, W->int4-in-int8 (reciprocal-mul) ------------------
__global__ __launch_bounds__(256) void quant2_kernel(const float* __restrict__ x,
                                                     signed char* __restrict__ qx, int n4x,
                                                     const unsigned* __restrict__ slotx,
                                                     const float* __restrict__ w,
                                                     signed char* __restrict__ qw, int n4w,
                                                     const unsigned* __restrict__ slotw) {
  const float4* src;
  int* dst;
  int n4, bid, nb;
  float qmaxv, qlo, qhi;
  const unsigned* slot;
  if (blockIdx.x < 1024) {
    src = (const float4*)x; dst = (int*)qx; n4 = n4x; bid = blockIdx.x; nb = 1024;
    slot = slotx; qmaxv = 127.0f; qlo = -128.0f; qhi = 127.0f;
  } else {
    src = (const float4*)w; dst = (int*)qw; n4 = n4w; bid = blockIdx.x - 1024; nb = 512;
    slot = slotw; qmaxv = 7.0f; qlo = -8.0f; qhi = 7.0f;
  }
  float s = fmaxf(__uint_as_float(*slot) / qmaxv, 1e-8f);
  float inv = 1.0f / s;
  int tid = bid * 256 + threadIdx.x;
  int stride = nb * 256;
  for (int i = tid; i < n4; i += stride) {
    float4 v = src[i];
    int a0 = (int)fminf(fmaxf(rintf(v.x * inv), qlo), qhi);
    int a1 = (int)fminf(fmaxf(rintf(v.y * inv), qlo), qhi);
    int a2 = (int)fminf(fmaxf(rintf(v.z * inv), qlo), qhi);
    int a3 = (int)fminf(fmaxf(rintf(v.w * inv), qlo), qhi);
    dst[i] = (a0 & 255) | ((a1 & 255) << 8) | ((a2 & 255) << 16) | ((a3 & 255) << 24);
  }
}

// ---------------- i8 GEMM, 256x256 tile, BK=128 B, 8 waves (2Mx4N), 32x32x32 MFMA -----------
// Per tile t (read db=t&1; stages fill ndb for t+1):
//   gate: if(t<31){STAGE B0(t+1); STAGE B1(t+1);} vmcnt(4) [t=31: vmcnt(0)]; barrier
//     outstanding at wait: 8 (tile t: B0,B1 from gate of t-1; A0,A1 from P0,P1 of t-1)
//     + 4 just issued -> vmcnt(4) drains exactly tile t. Youngest drained (A1(t), issued
//     P1 of t-1) is ~2.3 phases (~1500cyc) old -> HBM latency fully covered.
//   P0: 6 ds_read @ks0; STAGE A0(t+1); lgkmcnt(0); 8 MFMA; barrier
//   P1: 6 ds_read @ks1; STAGE A1(t+1); lgkmcnt(0); 8 MFMA; barrier
//   P2: 6 ds_read @ks2;               lgkmcnt(0); 8 MFMA; barrier
//   P3: 6 ds_read @ks3;               lgkmcnt(0); 8 MFMA; barrier
// WAR: every ndb write occurs after t-1's P3 barrier, by which all ndb reads completed
// (each phase's reads consumed before its lgkm->MFMA->barrier). Reads of t after its gate.
// LDS addr (row hr, phys g): (hr>>3)*1088 + (hr&7)*128 + g*16, g = g_log ^ (hr&7);
// inverse swizzle on global source granule (rule 21). Staging: 1024B linear per instruction
// at chunk base (i*8+w)*1088.
// C/D layout (m74/m101, dtype-independent): col=lane&31, row=(r&3)+8*(r>>2)+4*(lane>>5).
template <bool BF16OUT>
__global__ __launch_bounds__(512, 2) void gemm_i8_kernel(const signed char* __restrict__ Xq,
                                                         const signed char* __restrict__ Wq,
                                                         const float* __restrict__ bias,
                                                         const unsigned* __restrict__ slots,
                                                         void* __restrict__ Yout,
                                                         unsigned* __restrict__ maxY) {
  __shared__ signed char smem[8 * HT];  // 139264 B
  const int tid = threadIdx.x;
  const int wid = tid >> 6, lane = tid & 63;
  const int wr = wid >> 2, wc = wid & 3;
  const int l31 = lane & 31, lg2 = lane >> 5;

  const int bid = (int)blockIdx.x;
  const int swz = (bid & 7) * (NWG / 8) + (bid >> 3);  // XCD-aware bijective (512%8==0)
  const int brow = (swz / NBN) * 256;
  const int bcol = (swz % NBN) * 256;

  const int srr = tid >> 3;                 // staging row 0..63
  const int sgl = (tid & 7) ^ (srr & 7);    // inverse-swizzled source granule

  // per-frag LDS row-base offsets / swizzle keys (chunked layout)
  int aoff[4], asw[4], boff[2], bsw[2];
#pragma unroll
  for (int mm = 0; mm < 4; ++mm) {
    int hr = wr * 64 + (mm & 1) * 32 + l31;
    aoff[mm] = (hr >> 3) * CH + (hr & 7) * 128;
    asw[mm] = hr & 7;
  }
#pragma unroll
  for (int nn = 0; nn < 2; ++nn) {
    int hr = wc * 32 + l31;
    boff[nn] = (hr >> 3) * CH + (hr & 7) * 128;
    bsw[nn] = hr & 7;
  }

#define ASLOT(db, h) (smem + ((db) * 2 + (h)) * HT)
#define BSLOT(db, h) (smem + 4 * HT + ((db) * 2 + (h)) * HT)
// one half-tile (128 rows): 2 x global_load_lds(16B) per wave; chunk base (i*8+wid)*1088
#define STAGE(gptr, grow0, kofs, slot)                                                        \
  {                                                                                           \
    const signed char* _s0 = (gptr) + (size_t)((grow0) + srr) * GK + (kofs) + sgl * 16;       \
    __builtin_amdgcn_global_load_lds(AS1(_s0), AS3((slot) + wid * CH), 16, 0, 0);             \
    __builtin_amdgcn_global_load_lds(AS1(_s0 + (size_t)64 * GK),                              \
                                     AS3((slot) + (8 + wid) * CH), 16, 0, 0);                 \
  }
#define LDA32(mm, db, ks) \
  *(const v4i*)(ASLOT(db, (mm) >> 1) + aoff[mm] + ((((ks)*2 + lg2) ^ asw[mm]) << 4))
#define LDB32(nn, db, ks) \
  *(const v4i*)(BSLOT(db, nn) + boff[nn] + ((((ks)*2 + lg2) ^ bsw[nn]) << 4))
#define MFMA8()                                                                               \
  __builtin_amdgcn_s_setprio(1);                                                              \
  _Pragma("unroll") for (int mm = 0; mm < 4; ++mm)                                            \
      _Pragma("unroll") for (int nn = 0; nn < 2; ++nn) acc[mm][nn] =                          \
      __builtin_amdgcn_mfma_i32_32x32x32_i8(af[mm], bf[nn], acc[mm][nn], 0, 0, 0);            \
  __builtin_amdgcn_s_setprio(0);

  // prologue: tile 0's four halves (steady-state issue order: B0,B1 then A0,A1)
  STAGE(Wq, bcol, 0, BSLOT(0, 0));
  STAGE(Wq, bcol + 128, 0, BSLOT(0, 1));
  STAGE(Xq, brow, 0, ASLOT(0, 0));
  STAGE(Xq, brow + 128, 0, ASLOT(0, 1));

  v16i acc[4][2] = {};

#pragma unroll 2
  for (int t = 0; t < 32; ++t) {
    const int db = t & 1, ndb = db ^ 1;
    const int kof = (t + 1) * 128;
    v4i af[4], bf[2];

    // ---- gate: issue next B0+B1, drain this tile's four halves, sync
    if (t < 31) {
      STAGE(Wq, bcol, kof, BSLOT(ndb, 0));
      STAGE(Wq, bcol + 128, kof, BSLOT(ndb, 1));
    }
    if (t == 31)
      asm volatile("s_waitcnt vmcnt(0)" ::: "memory");
    else
      asm volatile("s_waitcnt vmcnt(4)" ::: "memory");
    __builtin_amdgcn_s_barrier();
    asm volatile("" ::: "memory");

    // ---- P0: ks=0; stage A0(t+1)
#pragma unroll
    for (int mm = 0; mm < 4; ++mm) af[mm] = LDA32(mm, db, 0);
#pragma unroll
    for (int nn = 0; nn < 2; ++nn) bf[nn] = LDB32(nn, db, 0);
    if (t < 31) STAGE(Xq, brow, kof, ASLOT(ndb, 0));
    asm volatile("s_waitcnt lgkmcnt(0)");
    MFMA8()
    __builtin_amdgcn_s_barrier();

    // ---- P1: ks=1; stage A1(t+1)
#pragma unroll
    for (int mm = 0; mm < 4; ++mm) af[mm] = LDA32(mm, db, 1);
#pragma unroll
    for (int nn = 0; nn < 2; ++nn) bf[nn] = LDB32(nn, db, 1);
    if (t < 31) STAGE(Xq, brow + 128, kof, ASLOT(ndb, 1));
    asm volatile("s_waitcnt lgkmcnt(0)");
    MFMA8()
    __builtin_amdgcn_s_barrier();

    // ---- P2: ks=2
#pragma unroll
    for (int mm = 0; mm < 4; ++mm) af[mm] = LDA32(mm, db, 2);
#pragma unroll
    for (int nn = 0; nn < 2; ++nn) bf[nn] = LDB32(nn, db, 2);
    asm volatile("s_waitcnt lgkmcnt(0)");
    MFMA8()
    __builtin_amdgcn_s_barrier();

    // ---- P3: ks=3
#pragma unroll
    for (int mm = 0; mm < 4; ++mm) af[mm] = LDA32(mm, db, 3);
#pragma unroll
    for (int nn = 0; nn < 2; ++nn) bf[nn] = LDB32(nn, db, 3);
    asm volatile("s_waitcnt lgkmcnt(0)");
    MFMA8()
    __builtin_amdgcn_s_barrier();
  }

  // Epilogue: y = acc*(s_in*s_w) + round(b/s_b)*s_b ; track max|y| (block-reduced atomic)
  float s_in = fmaxf(__uint_as_float(slots[0]) / 127.0f, 1e-8f);
  float s_w = fmaxf(__uint_as_float(slots[1]) / 7.0f, 1e-8f);
  float s_b = s_in * s_w;
  float bdq[2];
#pragma unroll
  for (int nn = 0; nn < 2; ++nn)
    bdq[nn] = rintf(bias[bcol + nn * 128 + wc * 32 + l31] / s_b) * s_b;
  float lmax = 0.0f;
#pragma unroll
  for (int m = 0; m < 4; ++m) {
    int rbase = brow + (m >> 1) * 128 + wr * 64 + (m & 1) * 32 + 4 * lg2;
#pragma unroll
    for (int n = 0; n < 2; ++n) {
      int o = bcol + n * 128 + wc * 32 + l31;
#pragma unroll
      for (int r = 0; r < 16; ++r) {
        int row = rbase + (r & 3) + 8 * (r >> 2);
        float yv = (float)acc[m][n][r] * s_b + bdq[n];
        size_t idx = (size_t)row * GN + o;
        if (BF16OUT) {
          unsigned u = __float_as_uint(yv);
          ((unsigned short*)Yout)[idx] = (unsigned short)((u + 0x7fffu + ((u >> 16) & 1u)) >> 16);
        } else {
          ((float*)Yout)[idx] = yv;
        }
        lmax = fmaxf(lmax, fabsf(yv));
      }
    }
  }
  for (int off = 32; off; off >>= 1) lmax = fmaxf(lmax, __shfl_xor(lmax, off));
  float* fred = (float*)smem;  // tile 31 read db=1 slots only; all reads drained
  if (lane == 0) fred[wid] = lmax;
  __syncthreads();
  if (tid == 0) {
    float m = fred[0];
#pragma unroll
    for (int i = 1; i < 8; ++i) m = fmaxf(m, fred[i]);
    atomicMax(maxY, __float_as_uint(m));
  }
#undef STAGE
#undef ASLOT
#undef BSLOT
#undef LDA32
#undef LDB32
#undef MFMA8
}

// ---------------- output quant: bf16 Y in ws -> quantized fp32 d_out -------------------------
__global__ __launch_bounds__(256) void quant_out_bf16_kernel(const unsigned short* __restrict__ yb,
                                                             float* __restrict__ out, int n8,
                                                             const unsigned* __restrict__ slot) {
  float s = fmaxf(__uint_as_float(*slot) / 127.0f, 1e-8f);
  float inv = 1.0f / s;
  int tid = blockIdx.x * blockDim.x + threadIdx.x;
  int stride = gridDim.x * blockDim.x;
  const uint4* y4 = (const uint4*)yb;
  float4* o4 = (float4*)out;
  for (int i = tid; i < n8; i += stride) {
    uint4 v = y4[i];
    float f[8];
    f[0] = __uint_as_float((v.x & 0xffffu) << 16);
    f[1] = __uint_as_float(v.x & 0xffff0000u);
    f[2] = __uint_as_float((v.y & 0xffffu) << 16);
    f[3] = __uint_as_float(v.y & 0xffff0000u);
    f[4] = __uint_as_float((v.z & 0xffffu) << 16);
    f[5] = __uint_as_float(v.z & 0xffff0000u);
    f[6] = __uint_as_float((v.w & 0xffffu) << 16);
    f[7] = __uint_as_float(v.w & 0xffff0000u);
    float4 a, b;
    a.x = fminf(fmaxf(rintf(f[0] * inv), -128.0f), 127.0f) * s;
    a.y = fminf(fmaxf(rintf(f[1] * inv), -128.0f), 127.0f) * s;
    a.z = fminf(fmaxf(rintf(f[2] * inv), -128.0f), 127.0f) * s;
    a.w = fminf(fmaxf(rintf(f[3] * inv), -128.0f), 127.0f) * s;
    b.x = fminf(fmaxf(rintf(f[4] * inv), -128.0f), 127.0f) * s;
    b.y = fminf(fmaxf(rintf(f[5] * inv), -128.0f), 127.0f) * s;
    b.z = fminf(fmaxf(rintf(f[6] * inv), -128.0f), 127.0f) * s;
    b.w = fminf(fmaxf(rintf(f[7] * inv), -128.0f), 127.0f) * s;
    o4[i * 2] = a;
    o4[i * 2 + 1] = b;
  }
}

// fp32 in-place fallback (ws too small for bf16 Y)
__global__ __launch_bounds__(256) void quant_out_kernel(float* __restrict__ y, int n4,
                                                        const unsigned* __restrict__ slot) {
  float s = fmaxf(__uint_as_float(*slot) / 127.0f, 1e-8f);
  float inv = 1.0f / s;
  int tid = blockIdx.x * blockDim.x + threadIdx.x;
  int stride = gridDim.x * blockDim.x;
  float4* y4 = (float4*)y;
  for (int i = tid; i < n4; i += stride) {
    float4 v = y4[i];
    v.x = fminf(fmaxf(rintf(v.x * inv), -128.0f), 127.0f) * s;
    v.y = fminf(fmaxf(rintf(v.y * inv), -128.0f), 127.0f) * s;
    v.z = fminf(fmaxf(rintf(v.z * inv), -128.0f), 127.0f) * s;
    v.w = fminf(fmaxf(rintf(v.w * inv), -128.0f), 127.0f) * s;
    y4[i] = v;
  }
}

extern "C" void kernel_launch(void* const* d_in, const int* in_sizes, int n_in,
                              void* d_out, int out_size, void* d_ws, size_t ws_size,
                              hipStream_t stream) {
  const float* inp = (const float*)d_in[0];  // [8192,4096]
  const float* W = (const float*)d_in[1];    // [4096,4096]
  const float* b = (const float*)d_in[2];    // [4096]
  float* out = (float*)d_out;                // [8192,4096]

  unsigned* slots = (unsigned*)d_ws;  // [0]=max|X|, [1]=max|W|, [2]=max|Y| (float bits)
  signed char* Xq = (signed char*)d_ws + 256;
  signed char* Wq = Xq + (size_t)GM * GK;
  unsigned short* Yb = (unsigned short*)(Wq + (size_t)GN * GK);

  const int nX = GM * GK;
  const int nW = GN * GK;
  const size_t need_bf16 = 256 + (size_t)nX + (size_t)nW + (size_t)GM * GN * 2;
  const bool use_bf16 = ws_size >= need_bf16;

  // zero the atomic-max slots (ws is NOT re-poisoned between timed replays)
  hipMemsetAsync(d_ws, 0, 16, stream);

  maxabs2_kernel<<<1536, 256, 0, stream>>>(inp, nX / 4, slots + 0, W, nW / 4, slots + 1);
  quant2_kernel<<<1536, 256, 0, stream>>>(inp, Xq, nX / 4, slots + 0, W, Wq, nW / 4, slots + 1);

  if (use_bf16) {
    gemm_i8_kernel<true><<<NWG, 512, 0, stream>>>(Xq, Wq, b, slots, (void*)Yb, slots + 2);
    quant_out_bf16_kernel<<<1024, 256, 0, stream>>>(Yb, out, (GM * GN) / 8, slots + 2);
  } else {
    gemm_i8_kernel<false><<<NWG, 512, 0, stream>>>(Xq, Wq, b, slots, (void*)out, slots + 2);
    quant_out_kernel<<<1024, 256, 0, stream>>>(out, (GM * GN) / 4, slots + 2);
  }
}

// Round 18
// 260.988 us; speedup vs baseline: 1.0986x; 1.0110x over previous
//
#include <hip/hip_runtime.h>

// ModelQuantLinear: int8-act × int4-weight per-tensor quantized linear, 8192×4096 @ 4096×4096^T.
// FINAL CONSOLIDATION: byte-exact r10 GEMM (best measured across 11 variants: 138us,
// mfma_i32_32x32x32_i8, 256x256 tile, BK=128B, 8 waves, 4-phase counted-vmcnt schedule,
// 1088B-chunk LDS) + bf16-Y epilogue + widened quant_out grid.

typedef int v4i __attribute__((ext_vector_type(4)));
typedef int v16i __attribute__((ext_vector_type(16)));

#define AS1(p) ((const __attribute__((address_space(1))) void*)(p))
#define AS3(p) ((__attribute__((address_space(3))) void*)(p))

#define GM 8192
#define GN 4096
#define GK 4096
#define NBN 16    // 4096/256 col tiles
#define NWG 512   // (8192/256)*(4096/256)
#define CH 1088   // chunk stride: 8 rows x 128B + 64B pad
#define HT 17408  // half-tile: 16 chunks x 1088

// ---------------- fused max|X|,max|W| (block ranges; float4, wave+block reduce, 1 atomic) ----
__global__ __launch_bounds__(256) void maxabs2_kernel(const float* __restrict__ x, int n4x,
                                                      unsigned* __restrict__ slotx,
                                                      const float* __restrict__ w, int n4w,
                                                      unsigned* __restrict__ slotw) {
  __shared__ float red[4];
  const float4* src;
  unsigned* slot;
  int n4, bid, nb;
  if (blockIdx.x < 1024) { src = (const float4*)x; slot = slotx; n4 = n4x; bid = blockIdx.x; nb = 1024; }
  else                   { src = (const float4*)w; slot = slotw; n4 = n4w; bid = blockIdx.x - 1024; nb = 512; }
  int tid = bid * 256 + threadIdx.x;
  int stride = nb * 256;
  float m = 0.0f;
  for (int i = tid; i < n4; i += stride) {
    float4 v = src[i];
    m = fmaxf(m, fmaxf(fmaxf(fabsf(v.x), fabsf(v.y)), fmaxf(fabsf(v.z), fabsf(v.w))));
  }
  for (int off = 32; off; off >>= 1) m = fmaxf(m, __shfl_xor(m, off));
  if ((threadIdx.x & 63) == 0) red[threadIdx.x >> 6] = m;
  __syncthreads();
  if (threadIdx.x == 0)
    atomicMax(slot, __float_as_uint(fmaxf(fmaxf(red[0], red[1]), fmaxf(red[2], red[3]))));
}

// ---------------- fused quantize X->int8, W->int4-in-int8 (reciprocal-mul) ------------------
__global__ __launch_bounds__(256) void quant2_kernel(const float* __restrict__ x,
                                                     signed char* __restrict__ qx, int n4x,
                                                     const unsigned* __restrict__ slotx,
                                                     const float* __restrict__ w,
                                                     signed char* __restrict__ qw, int n4w,
                                                     const unsigned* __restrict__ slotw) {
  const float4* src;
  int* dst;
  int n4, bid, nb;
  float qmaxv, qlo, qhi;
  const unsigned* slot;
  if (blockIdx.x < 1024) {
    src = (const float4*)x; dst = (int*)qx; n4 = n4x; bid = blockIdx.x; nb = 1024;
    slot = slotx; qmaxv = 127.0f; qlo = -128.0f; qhi = 127.0f;
  } else {
    src = (const float4*)w; dst = (int*)qw; n4 = n4w; bid = blockIdx.x - 1024; nb = 512;
    slot = slotw; qmaxv = 7.0f; qlo = -8.0f; qhi = 7.0f;
  }
  float s = fmaxf(__uint_as_float(*slot) / qmaxv, 1e-8f);
  float inv = 1.0f / s;
  int tid = bid * 256 + threadIdx.x;
  int stride = nb * 256;
  for (int i = tid; i < n4; i += stride) {
    float4 v = src[i];
    int a0 = (int)fminf(fmaxf(rintf(v.x * inv), qlo), qhi);
    int a1 = (int)fminf(fmaxf(rintf(v.y * inv), qlo), qhi);
    int a2 = (int)fminf(fmaxf(rintf(v.z * inv), qlo), qhi);
    int a3 = (int)fminf(fmaxf(rintf(v.w * inv), qlo), qhi);
    dst[i] = (a0 & 255) | ((a1 & 255) << 8) | ((a2 & 255) << 16) | ((a3 & 255) << 24);
  }
}

// ---------------- i8 GEMM (r10, best measured), 256x256 tile, BK=128 B, 8 waves (2Mx4N) -----
// Per tile t (read db=t&1; stages fill ndb):
//   gate: if(t<31) STAGE B0(t+1); vmcnt(2) [t=31: vmcnt(0)]; barrier  -> tile t in LDS
//   P(ks=0..3): 6 ds_read_b128 (af[4]+bf[2] @ ks); STAGE {B1,A0,A1}(t+1) at P0/P1/P2;
//               lgkmcnt(0); 8 x mfma_i32_32x32x32_i8; barrier
// LDS addr (row hr, phys g): (hr>>3)*1088 + (hr&7)*128 + g*16, g = g_log ^ (hr&7);
// inverse swizzle on global source granule (rule 21). Staging: 1024B linear per
// instruction at chunk base (i*8+w)*1088.
// C/D layout (m74/m101, dtype-independent): col=lane&31, row=(r&3)+8*(r>>2)+4*(lane>>5).
template <bool BF16OUT>
__global__ __launch_bounds__(512, 2) void gemm_i8_kernel(const signed char* __restrict__ Xq,
                                                         const signed char* __restrict__ Wq,
                                                         const float* __restrict__ bias,
                                                         const unsigned* __restrict__ slots,
                                                         void* __restrict__ Yout,
                                                         unsigned* __restrict__ maxY) {
  __shared__ signed char smem[8 * HT];  // 139264 B
  const int tid = threadIdx.x;
  const int wid = tid >> 6, lane = tid & 63;
  const int wr = wid >> 2, wc = wid & 3;
  const int l31 = lane & 31, lg2 = lane >> 5;

  const int bid = (int)blockIdx.x;
  const int swz = (bid & 7) * (NWG / 8) + (bid >> 3);  // XCD-aware bijective (512%8==0)
  const int brow = (swz / NBN) * 256;
  const int bcol = (swz % NBN) * 256;

  const int srr = tid >> 3;                 // staging row 0..63
  const int sgl = (tid & 7) ^ (srr & 7);    // inverse-swizzled source granule

  // per-frag LDS row-base offsets / swizzle keys (chunked layout)
  int aoff[4], asw[4], boff[2], bsw[2];
#pragma unroll
  for (int mm = 0; mm < 4; ++mm) {
    int hr = wr * 64 + (mm & 1) * 32 + l31;
    aoff[mm] = (hr >> 3) * CH + (hr & 7) * 128;
    asw[mm] = hr & 7;
  }
#pragma unroll
  for (int nn = 0; nn < 2; ++nn) {
    int hr = wc * 32 + l31;
    boff[nn] = (hr >> 3) * CH + (hr & 7) * 128;
    bsw[nn] = hr & 7;
  }

#define ASLOT(db, h) (smem + ((db) * 2 + (h)) * HT)
#define BSLOT(db, h) (smem + 4 * HT + ((db) * 2 + (h)) * HT)
// one half-tile (128 rows): 2 x global_load_lds(16B) per wave; chunk base (i*8+wid)*1088
#define STAGE(gptr, grow0, kofs, slot)                                                        \
  {                                                                                           \
    const signed char* _s0 = (gptr) + (size_t)((grow0) + srr) * GK + (kofs) + sgl * 16;       \
    __builtin_amdgcn_global_load_lds(AS1(_s0), AS3((slot) + wid * CH), 16, 0, 0);             \
    __builtin_amdgcn_global_load_lds(AS1(_s0 + (size_t)64 * GK),                              \
                                     AS3((slot) + (8 + wid) * CH), 16, 0, 0);                 \
  }
#define LDA32(mm, db, ks) \
  *(const v4i*)(ASLOT(db, (mm) >> 1) + aoff[mm] + ((((ks)*2 + lg2) ^ asw[mm]) << 4))
#define LDB32(nn, db, ks) \
  *(const v4i*)(BSLOT(db, nn) + boff[nn] + ((((ks)*2 + lg2) ^ bsw[nn]) << 4))
#define MFMA8()                                                                               \
  __builtin_amdgcn_s_setprio(1);                                                              \
  _Pragma("unroll") for (int mm = 0; mm < 4; ++mm)                                            \
      _Pragma("unroll") for (int nn = 0; nn < 2; ++nn) acc[mm][nn] =                          \
      __builtin_amdgcn_mfma_i32_32x32x32_i8(af[mm], bf[nn], acc[mm][nn], 0, 0, 0);            \
  __builtin_amdgcn_s_setprio(0);

  // prologue: tile 0's four halves (steady-state issue order)
  STAGE(Wq, bcol, 0, BSLOT(0, 0));
  STAGE(Wq, bcol + 128, 0, BSLOT(0, 1));
  STAGE(Xq, brow, 0, ASLOT(0, 0));
  STAGE(Xq, brow + 128, 0, ASLOT(0, 1));

  v16i acc[4][2] = {};

#pragma unroll 2
  for (int t = 0; t < 32; ++t) {
    const int db = t & 1, ndb = db ^ 1;
    const int kof = (t + 1) * 128;
    v4i af[4], bf[2];

    // ---- gate: issue next B0, drain this tile's four halves, sync
    if (t < 31) STAGE(Wq, bcol, kof, BSLOT(ndb, 0));
    if (t == 31)
      asm volatile("s_waitcnt vmcnt(0)" ::: "memory");
    else
      asm volatile("s_waitcnt vmcnt(2)" ::: "memory");
    __builtin_amdgcn_s_barrier();
    asm volatile("" ::: "memory");

    // ---- P0: ks=0; stage B1(t+1)
#pragma unroll
    for (int mm = 0; mm < 4; ++mm) af[mm] = LDA32(mm, db, 0);
#pragma unroll
    for (int nn = 0; nn < 2; ++nn) bf[nn] = LDB32(nn, db, 0);
    if (t < 31) STAGE(Wq, bcol + 128, kof, BSLOT(ndb, 1));
    asm volatile("s_waitcnt lgkmcnt(0)");
    MFMA8()
    __builtin_amdgcn_s_barrier();

    // ---- P1: ks=1; stage A0(t+1)
#pragma unroll
    for (int mm = 0; mm < 4; ++mm) af[mm] = LDA32(mm, db, 1);
#pragma unroll
    for (int nn = 0; nn < 2; ++nn) bf[nn] = LDB32(nn, db, 1);
    if (t < 31) STAGE(Xq, brow, kof, ASLOT(ndb, 0));
    asm volatile("s_waitcnt lgkmcnt(0)");
    MFMA8()
    __builtin_amdgcn_s_barrier();

    // ---- P2: ks=2; stage A1(t+1)
#pragma unroll
    for (int mm = 0; mm < 4; ++mm) af[mm] = LDA32(mm, db, 2);
#pragma unroll
    for (int nn = 0; nn < 2; ++nn) bf[nn] = LDB32(nn, db, 2);
    if (t < 31) STAGE(Xq, brow + 128, kof, ASLOT(ndb, 1));
    asm volatile("s_waitcnt lgkmcnt(0)");
    MFMA8()
    __builtin_amdgcn_s_barrier();

    // ---- P3: ks=3
#pragma unroll
    for (int mm = 0; mm < 4; ++mm) af[mm] = LDA32(mm, db, 3);
#pragma unroll
    for (int nn = 0; nn < 2; ++nn) bf[nn] = LDB32(nn, db, 3);
    asm volatile("s_waitcnt lgkmcnt(0)");
    MFMA8()
    __builtin_amdgcn_s_barrier();
  }

  // Epilogue: y = acc*(s_in*s_w) + round(b/s_b)*s_b ; track max|y| (block-reduced atomic)
  float s_in = fmaxf(__uint_as_float(slots[0]) / 127.0f, 1e-8f);
  float s_w = fmaxf(__uint_as_float(slots[1]) / 7.0f, 1e-8f);
  float s_b = s_in * s_w;
  float bdq[2];
#pragma unroll
  for (int nn = 0; nn < 2; ++nn)
    bdq[nn] = rintf(bias[bcol + nn * 128 + wc * 32 + l31] / s_b) * s_b;
  float lmax = 0.0f;
#pragma unroll
  for (int m = 0; m < 4; ++m) {
    int rbase = brow + (m >> 1) * 128 + wr * 64 + (m & 1) * 32 + 4 * lg2;
#pragma unroll
    for (int n = 0; n < 2; ++n) {
      int o = bcol + n * 128 + wc * 32 + l31;
#pragma unroll
      for (int r = 0; r < 16; ++r) {
        int row = rbase + (r & 3) + 8 * (r >> 2);
        float yv = (float)acc[m][n][r] * s_b + bdq[n];
        size_t idx = (size_t)row * GN + o;
        if (BF16OUT) {
          unsigned u = __float_as_uint(yv);
          ((unsigned short*)Yout)[idx] = (unsigned short)((u + 0x7fffu + ((u >> 16) & 1u)) >> 16);
        } else {
          ((float*)Yout)[idx] = yv;
        }
        lmax = fmaxf(lmax, fabsf(yv));
      }
    }
  }
  for (int off = 32; off; off >>= 1) lmax = fmaxf(lmax, __shfl_xor(lmax, off));
  float* fred = (float*)smem;  // tile 31 read db=1 slots only; all reads drained
  if (lane == 0) fred[wid] = lmax;
  __syncthreads();
  if (tid == 0) {
    float m = fred[0];
#pragma unroll
    for (int i = 1; i < 8; ++i) m = fmaxf(m, fred[i]);
    atomicMax(maxY, __float_as_uint(m));
  }
#undef STAGE
#undef ASLOT
#undef BSLOT
#undef LDA32
#undef LDB32
#undef MFMA8
}

// ---------------- output quant: bf16 Y in ws -> quantized fp32 d_out -------------------------
__global__ __launch_bounds__(256) void quant_out_bf16_kernel(const unsigned short* __restrict__ yb,
                                                             float* __restrict__ out, int n8,
                                                             const unsigned* __restrict__ slot) {
  float s = fmaxf(__uint_as_float(*slot) / 127.0f, 1e-8f);
  float inv = 1.0f / s;
  int tid = blockIdx.x * blockDim.x + threadIdx.x;
  int stride = gridDim.x * blockDim.x;
  const uint4* y4 = (const uint4*)yb;
  float4* o4 = (float4*)out;
  for (int i = tid; i < n8; i += stride) {
    uint4 v = y4[i];
    float f[8];
    f[0] = __uint_as_float((v.x & 0xffffu) << 16);
    f[1] = __uint_as_float(v.x & 0xffff0000u);
    f[2] = __uint_as_float((v.y & 0xffffu) << 16);
    f[3] = __uint_as_float(v.y & 0xffff0000u);
    f[4] = __uint_as_float((v.z & 0xffffu) << 16);
    f[5] = __uint_as_float(v.z & 0xffff0000u);
    f[6] = __uint_as_float((v.w & 0xffffu) << 16);
    f[7] = __uint_as_float(v.w & 0xffff0000u);
    float4 a, b;
    a.x = fminf(fmaxf(rintf(f[0] * inv), -128.0f), 127.0f) * s;
    a.y = fminf(fmaxf(rintf(f[1] * inv), -128.0f), 127.0f) * s;
    a.z = fminf(fmaxf(rintf(f[2] * inv), -128.0f), 127.0f) * s;
    a.w = fminf(fmaxf(rintf(f[3] * inv), -128.0f), 127.0f) * s;
    b.x = fminf(fmaxf(rintf(f[4] * inv), -128.0f), 127.0f) * s;
    b.y = fminf(fmaxf(rintf(f[5] * inv), -128.0f), 127.0f) * s;
    b.z = fminf(fmaxf(rintf(f[6] * inv), -128.0f), 127.0f) * s;
    b.w = fminf(fmaxf(rintf(f[7] * inv), -128.0f), 127.0f) * s;
    o4[i * 2] = a;
    o4[i * 2 + 1] = b;
  }
}

// fp32 in-place fallback (ws too small for bf16 Y)
__global__ __launch_bounds__(256) void quant_out_kernel(float* __restrict__ y, int n4,
                                                        const unsigned* __restrict__ slot) {
  float s = fmaxf(__uint_as_float(*slot) / 127.0f, 1e-8f);
  float inv = 1.0f / s;
  int tid = blockIdx.x * blockDim.x + threadIdx.x;
  int stride = gridDim.x * blockDim.x;
  float4* y4 = (float4*)y;
  for (int i = tid; i < n4; i += stride) {
    float4 v = y4[i];
    v.x = fminf(fmaxf(rintf(v.x * inv), -128.0f), 127.0f) * s;
    v.y = fminf(fmaxf(rintf(v.y * inv), -128.0f), 127.0f) * s;
    v.z = fminf(fmaxf(rintf(v.z * inv), -128.0f), 127.0f) * s;
    v.w = fminf(fmaxf(rintf(v.w * inv), -128.0f), 127.0f) * s;
    y4[i] = v;
  }
}

extern "C" void kernel_launch(void* const* d_in, const int* in_sizes, int n_in,
                              void* d_out, int out_size, void* d_ws, size_t ws_size,
                              hipStream_t stream) {
  const float* inp = (const float*)d_in[0];  // [8192,4096]
  const float* W = (const float*)d_in[1];    // [4096,4096]
  const float* b = (const float*)d_in[2];    // [4096]
  float* out = (float*)d_out;                // [8192,4096]

  unsigned* slots = (unsigned*)d_ws;  // [0]=max|X|, [1]=max|W|, [2]=max|Y| (float bits)
  signed char* Xq = (signed char*)d_ws + 256;
  signed char* Wq = Xq + (size_t)GM * GK;
  unsigned short* Yb = (unsigned short*)(Wq + (size_t)GN * GK);

  const int nX = GM * GK;
  const int nW = GN * GK;
  const size_t need_bf16 = 256 + (size_t)nX + (size_t)nW + (size_t)GM * GN * 2;
  const bool use_bf16 = ws_size >= need_bf16;

  // zero the atomic-max slots (ws is NOT re-poisoned between timed replays)
  hipMemsetAsync(d_ws, 0, 16, stream);

  maxabs2_kernel<<<1536, 256, 0, stream>>>(inp, nX / 4, slots + 0, W, nW / 4, slots + 1);
  quant2_kernel<<<1536, 256, 0, stream>>>(inp, Xq, nX / 4, slots + 0, W, Wq, nW / 4, slots + 1);

  if (use_bf16) {
    gemm_i8_kernel<true><<<NWG, 512, 0, stream>>>(Xq, Wq, b, slots, (void*)Yb, slots + 2);
    quant_out_bf16_kernel<<<2048, 256, 0, stream>>>(Yb, out, (GM * GN) / 8, slots + 2);
  } else {
    gemm_i8_kernel<false><<<NWG, 512, 0, stream>>>(Xq, Wq, b, slots, (void*)out, slots + 2);
    quant_out_kernel<<<2048, 256, 0, stream>>>(out, (GM * GN) / 4, slots + 2);
  }
}